// Round 1
// baseline (2119.165 us; speedup 1.0000x reference)
//
#include <hip/hip_runtime.h>
#include <hip/hip_bf16.h>

#define T_TOKENS 32768
#define HID 2048
#define EPSV 1e-6f

typedef __attribute__((ext_vector_type(8))) short short8;
typedef __attribute__((ext_vector_type(4))) float f32x4;

__device__ __forceinline__ unsigned short f2bf(float f) {
    unsigned u = __float_as_uint(f);
    unsigned r = (u + 0x7fffu + ((u >> 16) & 1u)) >> 16;
    return (unsigned short)r;
}

__device__ __forceinline__ void async_copy16(const void* g, void* l) {
    __builtin_amdgcn_global_load_lds(
        (const __attribute__((address_space(1))) void*)g,
        (__attribute__((address_space(3))) void*)l,
        16, 0, 0);
}

__device__ __forceinline__ float block_sum256(float v) {
    #pragma unroll
    for (int off = 32; off > 0; off >>= 1) v += __shfl_down(v, off, 64);
    __shared__ float smem[4];
    int w = threadIdx.x >> 6;
    if ((threadIdx.x & 63) == 0) smem[w] = v;
    __syncthreads();
    return smem[0] + smem[1] + smem[2] + smem[3];
}

// ---------------- W fp32 [k][n] -> bf16 transposed [n][k] ----------------
__global__ __launch_bounds__(256)
void transpose_cast(const float* __restrict__ W, unsigned short* __restrict__ Wt) {
    __shared__ float t[32][33];
    const int bx = blockIdx.x * 32;  // n base
    const int by = blockIdx.y * 32;  // k base
    #pragma unroll
    for (int i = threadIdx.y; i < 32; i += 8)
        t[i][threadIdx.x] = W[(long)(by + i) * HID + bx + threadIdx.x];
    __syncthreads();
    #pragma unroll
    for (int i = threadIdx.y; i < 32; i += 8)
        Wt[(long)(bx + i) * HID + by + threadIdx.x] = f2bf(t[threadIdx.x][i]);
}

// ---------------- prologue: resid = relu(x); y = rmsnorm(resid, g) bf16 ----------------
__global__ __launch_bounds__(256)
void relu_rmsnorm(const float* __restrict__ x, const float* __restrict__ g,
                  float* __restrict__ resid, unsigned short* __restrict__ y) {
    const long row = blockIdx.x;
    const float4* xr = (const float4*)(x + row * HID);
    float4 v[2];
    float ssq = 0.f;
    #pragma unroll
    for (int i = 0; i < 2; ++i) {
        int c = threadIdx.x + i * 256;
        float4 t = xr[c];
        t.x = fmaxf(t.x, 0.f); t.y = fmaxf(t.y, 0.f);
        t.z = fmaxf(t.z, 0.f); t.w = fmaxf(t.w, 0.f);
        ssq += t.x * t.x + t.y * t.y + t.z * t.z + t.w * t.w;
        v[i] = t;
    }
    float tot = block_sum256(ssq);
    float scale = rsqrtf(tot * (1.f / (float)HID) + EPSV);
    float4* rr = (float4*)(resid + row * HID);
    ushort4* yr = (ushort4*)(y + row * HID);
    const float4* gg = (const float4*)g;
    #pragma unroll
    for (int i = 0; i < 2; ++i) {
        int c = threadIdx.x + i * 256;
        rr[c] = v[i];
        float4 gv = gg[c];
        ushort4 o;
        o.x = f2bf(v[i].x * scale * gv.x);
        o.y = f2bf(v[i].y * scale * gv.y);
        o.z = f2bf(v[i].z * scale * gv.z);
        o.w = f2bf(v[i].w * scale * gv.w);
        yr[c] = o;
    }
}

// ---------------- mid/final rmsnorm: read resid, write y bf16 (mode 0) or fp32 out (mode 1) ----------------
__global__ __launch_bounds__(256)
void rmsnorm_stage(const float* __restrict__ resid, const float* __restrict__ g,
                   unsigned short* __restrict__ y, float* __restrict__ out, int mode) {
    const long row = blockIdx.x;
    const float4* rr = (const float4*)(resid + row * HID);
    float4 v[2];
    float ssq = 0.f;
    #pragma unroll
    for (int i = 0; i < 2; ++i) {
        int c = threadIdx.x + i * 256;
        float4 t = rr[c];
        ssq += t.x * t.x + t.y * t.y + t.z * t.z + t.w * t.w;
        v[i] = t;
    }
    float tot = block_sum256(ssq);
    float scale = rsqrtf(tot * (1.f / (float)HID) + EPSV);
    const float4* gg = (const float4*)g;
    if (mode == 0) {
        ushort4* yr = (ushort4*)(y + row * HID);
        #pragma unroll
        for (int i = 0; i < 2; ++i) {
            int c = threadIdx.x + i * 256;
            float4 gv = gg[c];
            ushort4 o;
            o.x = f2bf(v[i].x * scale * gv.x);
            o.y = f2bf(v[i].y * scale * gv.y);
            o.z = f2bf(v[i].z * scale * gv.z);
            o.w = f2bf(v[i].w * scale * gv.w);
            yr[c] = o;
        }
    } else {
        float4* orow = (float4*)(out + row * HID);
        #pragma unroll
        for (int i = 0; i < 2; ++i) {
            int c = threadIdx.x + i * 256;
            float4 gv = gg[c];
            float4 o;
            o.x = v[i].x * scale * gv.x;
            o.y = v[i].y * scale * gv.y;
            o.z = v[i].z * scale * gv.z;
            o.w = v[i].w * scale * gv.w;
            orow[c] = o;
        }
    }
}

// ---------------- GEMM: resid[M][N] += A[M][K](bf16) @ Bt[N][K](bf16)^T ----------------
// 128x128 tile, BK=32, 256 threads (4 waves, 2x2), each wave 64x64 via 4x4 of 16x16x32 MFMA.
#define BM 128
#define BN 128
#define BK 32

__global__ __launch_bounds__(256)
void gemm_bt_addres(const short* __restrict__ A, const short* __restrict__ Bt,
                    float* __restrict__ resid) {
    __shared__ short As[BM * BK];
    __shared__ short Bs[BN * BK];
    const int tid = threadIdx.x;
    const int lane = tid & 63;
    const int wid = tid >> 6;
    const int quad = lane >> 4;
    const int l16 = lane & 15;
    const int wm = (wid & 1) * 64;
    const int wn = (wid >> 1) * 64;
    const int bm = blockIdx.y * BM;
    const int bn = blockIdx.x * BN;
    const int K = HID, N = HID;

    f32x4 acc[4][4] = {};

    const long a_base = (long)bm * K;
    const long b_base = (long)bn * K;

    for (int kt = 0; kt < K; kt += BK) {
        __syncthreads();
        #pragma unroll
        for (int i = 0; i < 2; ++i) {
            int c = tid + i * 256;           // 512 chunks of 16B per tile
            int row = c >> 2, kc = c & 3;
            const short* ga = A + a_base + (long)row * K + kt + kc * 8;
            async_copy16(ga, &As[row * BK + kc * 8]);
            const short* gb = Bt + b_base + (long)row * K + kt + kc * 8;
            async_copy16(gb, &Bs[row * BK + kc * 8]);
        }
        __syncthreads();
        short8 a[4], b[4];
        #pragma unroll
        for (int i = 0; i < 4; ++i)
            a[i] = *(const short8*)&As[(wm + i * 16 + l16) * BK + quad * 8];
        #pragma unroll
        for (int j = 0; j < 4; ++j)
            b[j] = *(const short8*)&Bs[(wn + j * 16 + l16) * BK + quad * 8];
        #pragma unroll
        for (int i = 0; i < 4; ++i)
            #pragma unroll
            for (int j = 0; j < 4; ++j)
                acc[i][j] = __builtin_amdgcn_mfma_f32_16x16x32_bf16(a[i], b[j], acc[i][j], 0, 0, 0);
    }

    // epilogue: resid += C
    #pragma unroll
    for (int i = 0; i < 4; ++i) {
        #pragma unroll
        for (int j = 0; j < 4; ++j) {
            const int col = bn + wn + j * 16 + l16;
            #pragma unroll
            for (int r = 0; r < 4; ++r) {
                const int row = bm + wm + i * 16 + quad * 4 + r;
                float* p = resid + (long)row * N + col;
                *p += acc[i][j][r];
            }
        }
    }
}

extern "C" void kernel_launch(void* const* d_in, const int* in_sizes, int n_in,
                              void* d_out, int out_size, void* d_ws, size_t ws_size,
                              hipStream_t stream) {
    const float* x  = (const float*)d_in[0];
    const float* g0 = (const float*)d_in[1];
    const float* g1 = (const float*)d_in[2];
    const float* g2 = (const float*)d_in[3];
    const float* g3 = (const float*)d_in[4];
    const float* W0 = (const float*)d_in[5];
    const float* W1 = (const float*)d_in[6];
    const float* W2 = (const float*)d_in[7];
    float* out = (float*)d_out;

    // workspace layout (bf16 elements): y[T*H], Wt0[H*H], Wt1[H*H], Wt2[H*H]
    unsigned short* y   = (unsigned short*)d_ws;
    unsigned short* Wt0 = y + (size_t)T_TOKENS * HID;
    unsigned short* Wt1 = Wt0 + (size_t)HID * HID;
    unsigned short* Wt2 = Wt1 + (size_t)HID * HID;

    float* resid = out;  // d_out doubles as the fp32 residual buffer

    dim3 tb(32, 8);
    dim3 tg(HID / 32, HID / 32);
    transpose_cast<<<tg, tb, 0, stream>>>(W0, Wt0);
    transpose_cast<<<tg, tb, 0, stream>>>(W1, Wt1);
    transpose_cast<<<tg, tb, 0, stream>>>(W2, Wt2);

    relu_rmsnorm<<<T_TOKENS, 256, 0, stream>>>(x, g0, resid, y);

    dim3 gg(HID / BN, T_TOKENS / BM);
    gemm_bt_addres<<<gg, 256, 0, stream>>>((const short*)y, (const short*)Wt0, resid);
    rmsnorm_stage<<<T_TOKENS, 256, 0, stream>>>(resid, g1, y, nullptr, 0);

    gemm_bt_addres<<<gg, 256, 0, stream>>>((const short*)y, (const short*)Wt1, resid);
    rmsnorm_stage<<<T_TOKENS, 256, 0, stream>>>(resid, g2, y, nullptr, 0);

    gemm_bt_addres<<<gg, 256, 0, stream>>>((const short*)y, (const short*)Wt2, resid);
    rmsnorm_stage<<<T_TOKENS, 256, 0, stream>>>(resid, g3, nullptr, out, 1);
}